// Round 8
// baseline (594.677 us; speedup 1.0000x reference)
//
#include <hip/hip_runtime.h>

// GeneralizedInteractionNet on MI355X (gfx950). R8: barrier-free b-loop.
//
// Per layer:  M[n,D,d] = W[n,D,d]*h[n,d]
//   GEMM1: C[b,i,D] = sum_d Bi[b,i,d] * M[n,D,d]
//   GEMM2: R[b,i,D] = sum_f AT[n,i,f] * B0T[b,D,f]^T
//   out[b,n,D] = sum_i C[b,i,D]*R[b,i,D]
// i padded 40->64 (2 row tiles of 32); f padded 40->48 (3 K-steps of 16).
// Padding garbage annihilated by exact zeros in AT (rows i>=40, cols f>=40).
//
// R7 post-mortem: barriered per-n staging capped MfmaUtil at ~40% even at
// 4 waves/SIMD (grid == exactly 4 blocks/CU: zero slack, barrier convoys;
// per-wave issue density halved). R8 inverts: block owns an n-PAIR, stages
// M/AT once (28.7 KB, ONE barrier), then loops over 16 b with no barriers.
// b-data streams from L2 (~12.5 TB/s demand < 34.5 ceiling), XCD-swizzled
// (blkIdx = ng*128+bg -> XCD = bg%8) so each b's 14 KB pins to one XCD
// (~3.6 MB/XCD). Grid 2560 = 10 blocks/CU demand over 4 resident ->
// continuous backfill. Regs ~119 <= 128 @ (256,4).

typedef __bf16 bf16x8 __attribute__((ext_vector_type(8)));
typedef float  f32x16 __attribute__((ext_vector_type(16)));
typedef unsigned short us4 __attribute__((ext_vector_type(4)));

constexpr int BATCH = 2048;
constexpr int FDIM  = 40;
constexpr int DDIM  = 64;
constexpr int LAY   = 3;
constexpr int IPAD  = 64;   // i padded: 2 row-tiles of 32
constexpr int FPAD  = 48;   // f padded: 3 K-steps of 16
constexpr int NSPAN = 2;    // n per block
constexpr int NG    = FDIM / NSPAN;   // 20 n-groups
constexpr int BG    = 128;  // b-groups (multiple of 8 for XCD swizzle)
constexpr int BPB   = BATCH / BG;     // 16 b per block
constexpr int MB_BYTES  = DDIM * DDIM * 2;        // 8192
constexpr int AT_BYTES  = IPAD * FPAD * 2;        // 6144
constexpr int BUF_BYTES = MB_BYTES + AT_BYTES;    // 14336 per n

__device__ __forceinline__ unsigned short f2bf(float f) {
  union { float f; unsigned u; } v; v.f = f;
  unsigned r = v.u + 0x7fff + ((v.u >> 16) & 1);   // round-to-nearest-even
  return (unsigned short)(r >> 16);
}

// async 16B global->LDS; LDS dest = wave-uniform base + lane*16
__device__ __forceinline__ void async16(const void* g, void* l) {
  __builtin_amdgcn_global_load_lds(
      (const __attribute__((address_space(1))) unsigned int*)g,
      (__attribute__((address_space(3))) unsigned int*)l, 16, 0, 0);
}

// Vectorized prep (4 elems/thread, ushort4 writes):
//  M[l,n,D,d]  = W*h (bf16, natural layout)
//  AT[l,n,i64,f48] = alpha[l,f,i,n], zero-padded (i>=40 or f>=40 -> 0)
//  B0b[b,f,d]  = bf16(inputs)          (Bi operand for layer 0)
//  B0T[b,d,f48]= bf16(inputs[b,f,d]), f>=40 -> 0   (GEMM2 B operand)
__global__ void prep_k(const float* __restrict__ W, const float* __restrict__ h,
                       const float* __restrict__ alpha, const float* __restrict__ inputs,
                       unsigned short* __restrict__ M, unsigned short* __restrict__ AT,
                       unsigned short* __restrict__ B0b, unsigned short* __restrict__ B0T) {
  int j = blockIdx.x * blockDim.x + threadIdx.x;
  const int nM4 = LAY * FDIM * DDIM * DDIM / 4;    // 122880
  const int nA4 = LAY * FDIM * IPAD * FPAD / 4;    // 92160
  const int nB4 = BATCH * FDIM * DDIM / 4;         // 1310720
  const int nT4 = BATCH * DDIM * FPAD / 4;         // 1572864
  if (j < nM4) {
    int e  = j * 4;
    int d  = e & 63;
    int ln = e >> 12;
    float4 wv = *reinterpret_cast<const float4*>(W + e);
    float4 hv = *reinterpret_cast<const float4*>(h + ln * DDIM + d);
    us4 o = { f2bf(wv.x * hv.x), f2bf(wv.y * hv.y), f2bf(wv.z * hv.z), f2bf(wv.w * hv.w) };
    *reinterpret_cast<us4*>(M + e) = o;
    return;
  }
  j -= nM4;
  if (j < nA4) {
    int e  = j * 4;
    int f  = e % FPAD;
    int ii = (e / FPAD) % IPAD;
    int n  = (e / (FPAD * IPAD)) % FDIM;
    int l  = e / (FPAD * IPAD * FDIM);
    us4 o = {0, 0, 0, 0};
    if (ii < FDIM) {
#pragma unroll
      for (int k = 0; k < 4; ++k)
        if (f + k < FDIM)
          o[k] = f2bf(alpha[(((size_t)l * FDIM + f + k) * FDIM + ii) * FDIM + n]);
    }
    *reinterpret_cast<us4*>(AT + e) = o;
    return;
  }
  j -= nA4;
  if (j < nB4) {
    int e = j * 4;
    float4 v = *reinterpret_cast<const float4*>(inputs + e);
    us4 o = { f2bf(v.x), f2bf(v.y), f2bf(v.z), f2bf(v.w) };
    *reinterpret_cast<us4*>(B0b + e) = o;
    return;
  }
  j -= nB4;
  if (j >= nT4) return;
  {
    int e  = j * 4;
    int f  = e % FPAD;
    int d  = (e / FPAD) % DDIM;
    int b  = e / (FPAD * DDIM);
    us4 o = {0, 0, 0, 0};
#pragma unroll
    for (int k = 0; k < 4; ++k)
      if (f + k < FDIM)
        o[k] = f2bf(inputs[((size_t)b * FDIM + f + k) * DDIM + d]);
    *reinterpret_cast<us4*>(B0T + e) = o;
  }
}

// mfma_f32_32x32x16_bf16 conventions:
//   A[m=lane&31][k=8*(lane>>5)+j]  B[k=8*(lane>>5)+j][col=lane&31]
//   C/D: col=lane&31, row=(reg&3)+8*(reg>>2)+4*(lane>>5)   [HW-verified]
template <bool FINAL>
__global__ __launch_bounds__(256, 4) void layer_k(
    const unsigned short* __restrict__ Bi,   // bf16 [B][40][64] (prev layer / B0b)
    const unsigned short* __restrict__ B0T,  // bf16 [B][64][48]
    const unsigned short* __restrict__ Mt,   // [40][64][64] bf16
    const unsigned short* __restrict__ ATt,  // [40][64][48] bf16 zero-padded
    void* __restrict__ outp)                 // bf16 intermediate or f32 final
{
  __shared__ __align__(16) unsigned short smem[NSPAN * BUF_BYTES / 2];

  const int tid  = threadIdx.x;
  const int lane = tid & 63;
  const int w    = tid >> 6;                  // wave (0..3)
  const int b2   = w >> 1;                    // wave's b offset within pair
  const int dt   = w & 1;                     // wave's D-half
  const int c    = lane & 31;
  const int h    = lane >> 5;
  const int ng   = blockIdx.x / BG;           // n-group
  const int bg   = blockIdx.x % BG;           // b-group -> XCD bg%8
  const int n0   = ng * NSPAN;
  const int bBase = bg * BPB;

  // Stage M[n] (chunk-XOR-swizzled) + AT[n] for both n, once per block.
#pragma unroll
  for (int nn = 0; nn < NSPAN; ++nn) {
    const unsigned short* Mn = Mt  + (n0 + nn) * (DDIM * DDIM);
    const unsigned short* An = ATt + (n0 + nn) * (IPAD * FPAD);
    char* base = (char*)smem + nn * BUF_BYTES;
#pragma unroll
    for (int r = 0; r < 2; ++r) {             // 8KB of M
      int p  = r * 256 + tid;                 // 16B-chunk index
      int D  = p >> 3, pc = p & 7;
      int cd = pc ^ (D & 7);
      async16(Mn + D * DDIM + cd * 8, base + r * 4096 + w * 1024);
    }
    // AT: 6 KB = 384 chunks; round 0 all waves, round 1 waves 0,1 only.
    async16(An + tid * 8, base + MB_BYTES + w * 1024);
    if (w < 2)
      async16(An + (256 + tid) * 8, base + MB_BYTES + 4096 + w * 1024);
  }
  __syncthreads();   // the ONLY barrier: staging drained, LDS read-only after

  for (int bi = 0; bi < BPB / 2; ++bi) {
    const int b = bBase + bi * 2 + b2;

    // aBi[it][ks]: GEMM1 A (rows i, k=d); rows>=40 clamped (killed by R=0).
    bf16x8 aBi[2][4];
#pragma unroll
    for (int it = 0; it < 2; ++it) {
      int row = it * 32 + c; if (row > FDIM - 1) row = FDIM - 1;
#pragma unroll
      for (int ks = 0; ks < 4; ++ks)
        aBi[it][ks] = *reinterpret_cast<const bf16x8*>(
            Bi + ((size_t)b * FDIM + row) * DDIM + ks * 16 + h * 8);
    }
    // bT[ks]: GEMM2 B = B0T[b][D=dt*32+c][f], contiguous 16B per lane.
    bf16x8 bT[3];
#pragma unroll
    for (int ks = 0; ks < 3; ++ks)
      bT[ks] = *reinterpret_cast<const bf16x8*>(
          B0T + ((size_t)b * DDIM + dt * 32 + c) * FPAD + ks * 16 + h * 8);

#pragma unroll
    for (int nn = 0; nn < NSPAN; ++nn) {
      const char* bufp = (const char*)smem + nn * BUF_BYTES;

      // mb[ks]: GEMM1 B from swizzled M, row D = dt*32+c.
      bf16x8 mb[4];
#pragma unroll
      for (int ks = 0; ks < 4; ++ks) {
        int D  = dt * 32 + c;
        int pc = (ks * 2 + h) ^ (D & 7);
        mb[ks] = *reinterpret_cast<const bf16x8*>(bufp + D * 128 + pc * 16);
      }

      float pout = 0.f;
#pragma unroll
      for (int it = 0; it < 2; ++it) {
        bf16x8 at[3];
#pragma unroll
        for (int ks = 0; ks < 3; ++ks)
          at[ks] = *reinterpret_cast<const bf16x8*>(
              bufp + MB_BYTES + ((it * 32 + c) * FPAD + ks * 16 + h * 8) * 2);

        f32x16 aC = {0,0,0,0,0,0,0,0,0,0,0,0,0,0,0,0};
        f32x16 aR = {0,0,0,0,0,0,0,0,0,0,0,0,0,0,0,0};
#pragma unroll
        for (int ks = 0; ks < 4; ++ks)
          aC = __builtin_amdgcn_mfma_f32_32x32x16_bf16(aBi[it][ks], mb[ks], aC, 0, 0, 0);
#pragma unroll
        for (int ks = 0; ks < 3; ++ks)
          aR = __builtin_amdgcn_mfma_f32_32x32x16_bf16(at[ks], bT[ks], aR, 0, 0, 0);

        // Combine: 4 independent partial chains (depth 4).
        float t0 = 0.f, t1 = 0.f, t2 = 0.f, t3 = 0.f;
#pragma unroll
        for (int r = 0; r < 4; ++r) {
          t0 += aC[r] * aR[r];         t1 += aC[r + 4] * aR[r + 4];
          t2 += aC[r + 8] * aR[r + 8]; t3 += aC[r + 12] * aR[r + 12];
        }
        pout += (t0 + t1) + (t2 + t3);
      }

      // finish i-sum across lane halves; lanes 0..31 store D = dt*32 + lane.
      float v = pout + __shfl_xor(pout, 32, 64);
      if (lane < 32) {
        size_t off = ((size_t)b * FDIM + (n0 + nn)) * DDIM + dt * 32 + lane;
        if (FINAL) ((float*)outp)[off] = v;
        else       ((unsigned short*)outp)[off] = f2bf(v);
      }
    }
  }
}

extern "C" void kernel_launch(void* const* d_in, const int* in_sizes, int n_in,
                              void* d_out, int out_size, void* d_ws, size_t ws_size,
                              hipStream_t stream) {
  const float* inputs = (const float*)d_in[0];  // [2048,40,64]
  const float* W      = (const float*)d_in[1];  // [3,40,64,64]
  const float* alpha  = (const float*)d_in[2];  // [3,40,40,40]
  const float* h      = (const float*)d_in[3];  // [3,40,64,1]

  char* ws = (char*)d_ws;
  const size_t S   = (size_t)BATCH * FDIM * DDIM * 2;   // 10.49 MB bf16 buffer
  const size_t ST  = (size_t)BATCH * DDIM * FPAD * 2;   // 12.58 MB B0T
  unsigned short* Bi1 = (unsigned short*)(ws);
  unsigned short* Bi2 = (unsigned short*)(ws + S);
  unsigned short* B0b = (unsigned short*)(ws + 2 * S);
  unsigned short* B0T = (unsigned short*)(ws + 3 * S);
  unsigned short* Mb  = (unsigned short*)(ws + 3 * S + ST);
  unsigned short* ATb = (unsigned short*)(ws + 3 * S + ST + (size_t)LAY * FDIM * DDIM * DDIM * 2);

  const int nPrep4 = (LAY * FDIM * DDIM * DDIM + LAY * FDIM * IPAD * FPAD
                    + BATCH * FDIM * DDIM + BATCH * DDIM * FPAD) / 4;
  prep_k<<<(nPrep4 + 255) / 256, 256, 0, stream>>>(W, h, alpha, inputs, Mb, ATb, B0b, B0T);

  dim3 grid(NG * BG), blk(256);   // 2560 blocks, XCD = blkIdx%8 = bg%8
  const size_t mL = (size_t)FDIM * DDIM * DDIM;
  const size_t aL = (size_t)FDIM * IPAD * FPAD;
  layer_k<false><<<grid, blk, 0, stream>>>(B0b, B0T, Mb, ATb, Bi1);
  layer_k<false><<<grid, blk, 0, stream>>>(Bi1, B0T, Mb + mL, ATb + aL, Bi2);
  layer_k<true ><<<grid, blk, 0, stream>>>(Bi2, B0T, Mb + 2 * mL, ATb + 2 * aL, d_out);
}

// Round 9
// 263.190 us; speedup vs baseline: 2.2595x; 2.2595x over previous
//
#include <hip/hip_runtime.h>

// GeneralizedInteractionNet on MI355X (gfx950). R9: barrier-free, LDS-free —
// per-n operands read directly from L2.
//
// Per layer:  M[n,D,d] = W[n,D,d]*h[n,d]
//   GEMM1: C[b,i,D] = sum_d Bi[b,i,d] * M[n,D,d]
//   GEMM2: R[b,i,D] = sum_f AT[n,i,f] * B0T[b,D,f]^T
//   out[b,n,D] = sum_i C[b,i,D]*R[b,i,D]
// i padded 40->64 (2 row tiles of 32); f padded 40->48 (3 K-steps of 16).
// Padding garbage annihilated by exact zeros in AT (rows i>=40, cols f>=40).
//
// History: R5 (LDS-staged, barriered, 2 waves/SIMD) = 65.6 us/layer,
// MfmaUtil 46% — stall is the per-iter __syncthreads (vmcnt(0) drain of
// stores+DMA, wave convoy). R6/R8 spilling: launch_bounds caps the UNIFIED
// VGPR+AGPR file. R8's n-major b-loop: b-data refetch went to HBM (510 MB)
// — XCD pinning doesn't hold; b-major layout is mandatory for ideal FETCH.
// R9 = R5 minus LDS/DMA/barriers: M[n]+AT[n] fragments (14 KB/n) are
// L2-resident (573 KB/layer); 14 direct b128 loads per wave-n. GEMM1 B-frag
// from natural M: B[k=d][col=D]=M[D][d] -> lane(c,h) reads row c, 16B chunk.
// No barrier -> compiler hoists next-n loads across the store tail; stores
// fire-and-forget. nsplit 4 -> grid 2048 (2 generations, backfill slack).

typedef __bf16 bf16x8 __attribute__((ext_vector_type(8)));
typedef float  f32x16 __attribute__((ext_vector_type(16)));
typedef unsigned short us4 __attribute__((ext_vector_type(4)));

constexpr int BATCH = 2048;
constexpr int FDIM  = 40;
constexpr int DDIM  = 64;
constexpr int LAY   = 3;
constexpr int IPAD  = 64;   // i padded: 2 row-tiles of 32
constexpr int FPAD  = 48;   // f padded: 3 K-steps of 16
constexpr int NSPL  = 4;    // n-loop split across 4 blocks
constexpr int NPB   = FDIM / NSPL;    // 10 n per block

__device__ __forceinline__ unsigned short f2bf(float f) {
  union { float f; unsigned u; } v; v.f = f;
  unsigned r = v.u + 0x7fff + ((v.u >> 16) & 1);   // round-to-nearest-even
  return (unsigned short)(r >> 16);
}

// Vectorized prep (4 elems/thread, ushort4 writes):
//  M[l,n,D,d]  = W*h (bf16, natural layout)
//  AT[l,n,i64,f48] = alpha[l,f,i,n], zero-padded (i>=40 or f>=40 -> 0)
//  B0b[b,f,d]  = bf16(inputs)          (Bi operand for layer 0)
//  B0T[b,d,f48]= bf16(inputs[b,f,d]), f>=40 -> 0   (GEMM2 B operand)
__global__ void prep_k(const float* __restrict__ W, const float* __restrict__ h,
                       const float* __restrict__ alpha, const float* __restrict__ inputs,
                       unsigned short* __restrict__ M, unsigned short* __restrict__ AT,
                       unsigned short* __restrict__ B0b, unsigned short* __restrict__ B0T) {
  int j = blockIdx.x * blockDim.x + threadIdx.x;
  const int nM4 = LAY * FDIM * DDIM * DDIM / 4;    // 122880
  const int nA4 = LAY * FDIM * IPAD * FPAD / 4;    // 92160
  const int nB4 = BATCH * FDIM * DDIM / 4;         // 1310720
  const int nT4 = BATCH * DDIM * FPAD / 4;         // 1572864
  if (j < nM4) {
    int e  = j * 4;
    int d  = e & 63;
    int ln = e >> 12;
    float4 wv = *reinterpret_cast<const float4*>(W + e);
    float4 hv = *reinterpret_cast<const float4*>(h + ln * DDIM + d);
    us4 o = { f2bf(wv.x * hv.x), f2bf(wv.y * hv.y), f2bf(wv.z * hv.z), f2bf(wv.w * hv.w) };
    *reinterpret_cast<us4*>(M + e) = o;
    return;
  }
  j -= nM4;
  if (j < nA4) {
    int e  = j * 4;
    int f  = e % FPAD;
    int ii = (e / FPAD) % IPAD;
    int n  = (e / (FPAD * IPAD)) % FDIM;
    int l  = e / (FPAD * IPAD * FDIM);
    us4 o = {0, 0, 0, 0};
    if (ii < FDIM) {
#pragma unroll
      for (int k = 0; k < 4; ++k)
        if (f + k < FDIM)
          o[k] = f2bf(alpha[(((size_t)l * FDIM + f + k) * FDIM + ii) * FDIM + n]);
    }
    *reinterpret_cast<us4*>(AT + e) = o;
    return;
  }
  j -= nA4;
  if (j < nB4) {
    int e = j * 4;
    float4 v = *reinterpret_cast<const float4*>(inputs + e);
    us4 o = { f2bf(v.x), f2bf(v.y), f2bf(v.z), f2bf(v.w) };
    *reinterpret_cast<us4*>(B0b + e) = o;
    return;
  }
  j -= nB4;
  if (j >= nT4) return;
  {
    int e  = j * 4;
    int f  = e % FPAD;
    int d  = (e / FPAD) % DDIM;
    int b  = e / (FPAD * DDIM);
    us4 o = {0, 0, 0, 0};
#pragma unroll
    for (int k = 0; k < 4; ++k)
      if (f + k < FDIM)
        o[k] = f2bf(inputs[((size_t)b * FDIM + f + k) * DDIM + d]);
    *reinterpret_cast<us4*>(B0T + e) = o;
  }
}

// mfma_f32_32x32x16_bf16 conventions:
//   A[m=lane&31][k=8*(lane>>5)+j]  B[k=8*(lane>>5)+j][col=lane&31]
//   C/D: col=lane&31, row=(reg&3)+8*(reg>>2)+4*(lane>>5)   [HW-verified]
template <bool FINAL>
__global__ __launch_bounds__(128, 2) void layer_k(
    const unsigned short* __restrict__ Bi,   // bf16 [B][40][64] (prev layer / B0b)
    const unsigned short* __restrict__ B0T,  // bf16 [B][64][48]
    const unsigned short* __restrict__ Mt,   // [40][64][64] bf16
    const unsigned short* __restrict__ ATt,  // [40][64][48] bf16 zero-padded
    void* __restrict__ outp)                 // bf16 intermediate or f32 final
{
  const int tid  = threadIdx.x;
  const int lane = tid & 63;
  const int w    = tid >> 6;                  // wave in block (0,1)
  const int c    = lane & 31;
  const int h    = lane >> 5;
  const int bg   = blockIdx.x >> 2;           // 512 b-groups of 4 b
  const int nBase = (blockIdx.x & 3) * NPB;   // this block's n range
  const int bb   = bg * 4 + w * 2;            // wave's first batch element

  // ---- wave-constant register fragments (loaded once, reused over 10 n) ----
  // aBi[b2][it][ks]: GEMM1 A (rows i, k=d); rows>=40 clamped (killed by R=0).
  bf16x8 aBi[2][2][4];
#pragma unroll
  for (int b2 = 0; b2 < 2; ++b2)
#pragma unroll
    for (int it = 0; it < 2; ++it) {
      int row = it * 32 + c; if (row > FDIM - 1) row = FDIM - 1;
#pragma unroll
      for (int ks = 0; ks < 4; ++ks)
        aBi[b2][it][ks] = *reinterpret_cast<const bf16x8*>(
            Bi + ((size_t)(bb + b2) * FDIM + row) * DDIM + ks * 16 + h * 8);
    }

  // bT[b2][dt][ks]: GEMM2 B = B0T[b][D][f], contiguous 16B per lane.
  bf16x8 bT[2][2][3];
#pragma unroll
  for (int b2 = 0; b2 < 2; ++b2)
#pragma unroll
    for (int dt = 0; dt < 2; ++dt)
#pragma unroll
      for (int ks = 0; ks < 3; ++ks)
        bT[b2][dt][ks] = *reinterpret_cast<const bf16x8*>(
            B0T + ((size_t)(bb + b2) * DDIM + dt * 32 + c) * FPAD + ks * 16 + h * 8);

  for (int ln = 0; ln < NPB; ++ln) {
    const int n = nBase + ln;
    const unsigned short* Mn = Mt  + n * (DDIM * DDIM);
    const unsigned short* An = ATt + n * (IPAD * FPAD);

    // Per-n operands straight from L2 (M/AT are L2-resident: 573 KB/layer).
    // mb[dt][ks]: GEMM1 B-frag. B[k=d][col=D] = M[D][d]: lane (c,h) reads
    // row D = dt*32+c, bytes [ks*32 + h*16, +16) -- contiguous b128.
    bf16x8 mb[2][4];
#pragma unroll
    for (int dt = 0; dt < 2; ++dt)
#pragma unroll
      for (int ks = 0; ks < 4; ++ks)
        mb[dt][ks] = *reinterpret_cast<const bf16x8*>(
            Mn + (dt * 32 + c) * DDIM + ks * 16 + h * 8);

    // at[it][ks]: GEMM2 A-frag. A[m=i][k=f]: row i = it*32+c, contiguous b128.
    bf16x8 at[2][3];
#pragma unroll
    for (int it = 0; it < 2; ++it)
#pragma unroll
      for (int ks = 0; ks < 3; ++ks)
        at[it][ks] = *reinterpret_cast<const bf16x8*>(
            An + (it * 32 + c) * FPAD + ks * 16 + h * 8);

    float pout[2][2] = {{0.f, 0.f}, {0.f, 0.f}};   // [b2][dt]

#pragma unroll
    for (int it = 0; it < 2; ++it) {
#pragma unroll
      for (int dt = 0; dt < 2; ++dt) {
        // Two independent (b2) chain pairs interleaved -> MFMA pipe stays fed.
        f32x16 aC0 = {0,0,0,0,0,0,0,0,0,0,0,0,0,0,0,0};
        f32x16 aC1 = {0,0,0,0,0,0,0,0,0,0,0,0,0,0,0,0};
        f32x16 aR0 = {0,0,0,0,0,0,0,0,0,0,0,0,0,0,0,0};
        f32x16 aR1 = {0,0,0,0,0,0,0,0,0,0,0,0,0,0,0,0};
#pragma unroll
        for (int ks = 0; ks < 4; ++ks) {
          aC0 = __builtin_amdgcn_mfma_f32_32x32x16_bf16(aBi[0][it][ks], mb[dt][ks], aC0, 0, 0, 0);
          aC1 = __builtin_amdgcn_mfma_f32_32x32x16_bf16(aBi[1][it][ks], mb[dt][ks], aC1, 0, 0, 0);
        }
#pragma unroll
        for (int ks = 0; ks < 3; ++ks) {
          aR0 = __builtin_amdgcn_mfma_f32_32x32x16_bf16(at[it][ks], bT[0][dt][ks], aR0, 0, 0, 0);
          aR1 = __builtin_amdgcn_mfma_f32_32x32x16_bf16(at[it][ks], bT[1][dt][ks], aR1, 0, 0, 0);
        }
        // Combine: 4 independent partial chains per b2 (depth 4, not 16).
        {
          float t0 = 0.f, t1 = 0.f, t2 = 0.f, t3 = 0.f;
#pragma unroll
          for (int r = 0; r < 4; ++r) {
            t0 += aC0[r] * aR0[r];         t1 += aC0[r + 4] * aR0[r + 4];
            t2 += aC0[r + 8] * aR0[r + 8]; t3 += aC0[r + 12] * aR0[r + 12];
          }
          pout[0][dt] += (t0 + t1) + (t2 + t3);
        }
        {
          float t0 = 0.f, t1 = 0.f, t2 = 0.f, t3 = 0.f;
#pragma unroll
          for (int r = 0; r < 4; ++r) {
            t0 += aC1[r] * aR1[r];         t1 += aC1[r + 4] * aR1[r + 4];
            t2 += aC1[r + 8] * aR1[r + 8]; t3 += aC1[r + 12] * aR1[r + 12];
          }
          pout[1][dt] += (t0 + t1) + (t2 + t3);
        }
      }
    }

    // finish i-sum across lane halves; lane stores D = 16*?.. D = h-selected
    // half: lane stores D = dt*32 + c with dt = h, i.e. D = lane (coalesced).
#pragma unroll
    for (int b2 = 0; b2 < 2; ++b2) {
      float v0 = pout[b2][0] + __shfl_xor(pout[b2][0], 32, 64);
      float v1 = pout[b2][1] + __shfl_xor(pout[b2][1], 32, 64);
      float val = h ? v1 : v0;
      size_t off = ((size_t)(bb + b2) * FDIM + n) * DDIM + lane;
      if (FINAL) ((float*)outp)[off] = val;
      else       ((unsigned short*)outp)[off] = f2bf(val);
    }
  }
}

extern "C" void kernel_launch(void* const* d_in, const int* in_sizes, int n_in,
                              void* d_out, int out_size, void* d_ws, size_t ws_size,
                              hipStream_t stream) {
  const float* inputs = (const float*)d_in[0];  // [2048,40,64]
  const float* W      = (const float*)d_in[1];  // [3,40,64,64]
  const float* alpha  = (const float*)d_in[2];  // [3,40,40,40]
  const float* h      = (const float*)d_in[3];  // [3,40,64,1]

  char* ws = (char*)d_ws;
  const size_t S   = (size_t)BATCH * FDIM * DDIM * 2;   // 10.49 MB bf16 buffer
  const size_t ST  = (size_t)BATCH * DDIM * FPAD * 2;   // 12.58 MB B0T
  unsigned short* Bi1 = (unsigned short*)(ws);
  unsigned short* Bi2 = (unsigned short*)(ws + S);
  unsigned short* B0b = (unsigned short*)(ws + 2 * S);
  unsigned short* B0T = (unsigned short*)(ws + 3 * S);
  unsigned short* Mb  = (unsigned short*)(ws + 3 * S + ST);
  unsigned short* ATb = (unsigned short*)(ws + 3 * S + ST + (size_t)LAY * FDIM * DDIM * DDIM * 2);

  const int nPrep4 = (LAY * FDIM * DDIM * DDIM + LAY * FDIM * IPAD * FPAD
                    + BATCH * FDIM * DDIM + BATCH * DDIM * FPAD) / 4;
  prep_k<<<(nPrep4 + 255) / 256, 256, 0, stream>>>(W, h, alpha, inputs, Mb, ATb, B0b, B0T);

  dim3 grid(BATCH / 4 * NSPL), blk(128);   // 2048 blocks, 2 waves each
  const size_t mL = (size_t)FDIM * DDIM * DDIM;
  const size_t aL = (size_t)FDIM * IPAD * FPAD;
  layer_k<false><<<grid, blk, 0, stream>>>(B0b, B0T, Mb, ATb, Bi1);
  layer_k<false><<<grid, blk, 0, stream>>>(Bi1, B0T, Mb + mL, ATb + aL, Bi2);
  layer_k<true ><<<grid, blk, 0, stream>>>(Bi2, B0T, Mb + 2 * mL, ATb + 2 * aL, d_out);
}